// Round 12
// baseline (66.491 us; speedup 1.0000x reference)
//
#include <hip/hip_runtime.h>

// Problem constants: B=2, L=32, C=8, H=W=64
#define BB 2
#define LL 32
#define CC 8
#define HH 64
#define WW 64
#define HWL 4096

typedef _Float16 h2 __attribute__((ext_vector_type(2)));

#if defined(__has_builtin)
#if __has_builtin(__builtin_amdgcn_fdot2)
#define HAVE_FDOT2 1
#endif
#endif

__device__ __forceinline__ float fdot2f(uint32_t a, uint32_t b, float c) {
    union { uint32_t u; h2 h; } ua, ub;
    ua.u = a;
    ub.u = b;
#ifdef HAVE_FDOT2
    return __builtin_amdgcn_fdot2(ua.h, ub.h, c, false);
#else
    return c + (float)ua.h.x * (float)ub.h.x + (float)ua.h.y * (float)ub.h.y;
#endif
}

__device__ __forceinline__ uint32_t pkh2(float lo, float hi) {
    union { h2 h; uint32_t u; } v;
    v.h.x = (_Float16)lo;
    v.h.y = (_Float16)hi;
    return v.u;
}

// ---------------------------------------------------------------------------
// Fused prep kernel.
// Blocks [0,64): flow cumsum over B*2*H*W = 16384 threads (r10-proven).
// Blocks [64,576): build 2x2-pixel x 2-channel 16B records:
//   plane p = (b*LL+l)*4 + cg (cg in [0,4), channels {2cg, 2cg+1}).
//   rec(ya, xa), ya,xa in [0,64): uint4
//     w.x = (c0[ya][xa],   c0[ya][xa+1])     w.y = (c1[ya][xa],  c1[ya][xa+1])
//     w.z = (c0[ya+1][xa], c0[ya+1][xa+1])   w.w = (c1[ya+1][..])
//   with col 64 and row 64 = 0 pad. One aligned 16B gather = whole sample.
// ---------------------------------------------------------------------------
#define CUM_BLOCKS 64

__global__ __launch_bounds__(256) void prep_kernel(
    const float* __restrict__ flows, const float* __restrict__ img,
    float* __restrict__ cum, uint32_t* __restrict__ planes) {
    int bid = blockIdx.x;
    if (bid < CUM_BLOCKS) {
        int idx  = bid * 256 + threadIdx.x;  // over B*2*H*W = 16384
        if (idx >= BB * 2 * HWL) return;
        int pix  = idx & (HWL - 1);
        int rest = idx >> 12;  // b*2 + comp, in [0,4)
        int comp = rest & 1;
        int b    = rest >> 1;
        size_t base = ((size_t)(b * LL) * 2 + comp) * HWL + pix;
        float v[LL];
#pragma unroll
        for (int l = 0; l < LL; ++l) v[l] = flows[base + (size_t)l * 2 * HWL];
        float acc = 0.0f;
#pragma unroll
        for (int l = 0; l < LL; ++l) {
            acc += v[l];
            cum[base + (size_t)l * 2 * HWL] = acc;
        }
    } else {
        int idx = (bid - CUM_BLOCKS) * 256 + threadIdx.x;  // over 64*64*32
        if (idx >= BB * LL * HH * 32) return;
        int r  = idx & 31;         // xa pair {2r, 2r+1}
        int ya = (idx >> 5) & 63;
        int bl = idx >> 11;        // b*32 + l, in [0,64)
        bool lastx = (r == 31);
        bool lasty = (ya == 63);
        const float* ip = img + (size_t)bl * CC * HWL + ya * WW + 2 * r;
        // rows ya (t) and ya+1 (u); 3 columns {2r, 2r+1, 2r+2}
        float t0[8], t1[8], t2[8], u0[8], u1[8], u2[8];
#pragma unroll
        for (int c = 0; c < 8; ++c) {
            const float* rp = ip + (size_t)c * HWL;
            float2 A = *reinterpret_cast<const float2*>(rp);
            t0[c] = A.x;
            t1[c] = A.y;
            t2[c] = lastx ? 0.0f : rp[2];
            if (!lasty) {
                float2 Bv = *reinterpret_cast<const float2*>(rp + WW);
                u0[c] = Bv.x;
                u1[c] = Bv.y;
                u2[c] = lastx ? 0.0f : rp[WW + 2];
            } else {
                u0[c] = 0.0f;
                u1[c] = 0.0f;
                u2[c] = 0.0f;
            }
        }
        uint4* P = reinterpret_cast<uint4*>(planes);
#pragma unroll
        for (int cg = 0; cg < 4; ++cg) {
            int c0 = 2 * cg, c1 = 2 * cg + 1;
            uint4 e, o;  // recs xa = 2r (even) and 2r+1 (odd)
            e.x = pkh2(t0[c0], t1[c0]);
            e.y = pkh2(t0[c1], t1[c1]);
            e.z = pkh2(u0[c0], u1[c0]);
            e.w = pkh2(u0[c1], u1[c1]);
            o.x = pkh2(t1[c0], t2[c0]);
            o.y = pkh2(t1[c1], t2[c1]);
            o.z = pkh2(u1[c0], u2[c0]);
            o.w = pkh2(u1[c1], u2[c1]);
            size_t base = (size_t)(bl * 4 + cg) * 4096 + ya * 64 + 2 * r;
            P[base]     = e;
            P[base + 1] = o;
        }
    }
}

// ---------------------------------------------------------------------------
// prep_s2: grid math -> one record offset + packed top/bottom row weights.
// Weight values identical to rounds 3-11 (x-shuffle for x0=-1; y handled by
// htop/hbot select: y0=-1 -> htop=h1,hbot=0; y0=63 -> pad row x h1=0).
// ---------------------------------------------------------------------------
__device__ __forceinline__ void prep_s2(float axv, float ayv, float ckx,
                                        float cky, int& off, uint32_t& htop,
                                        uint32_t& hbot) {
    float aa = axv - ckx;                // == g0 + 1 (±1ulp reassoc, r11-proven)
    float hh = aa * 0.5f;
    float fh = floorf(hh);
    float tt = fmaf(fh, -64.0f, -0.5f);  // exact
    float ix = fmaf(aa, 32.0f, tt);      // in [-0.5, 63.5)
    float ay = ayv - cky;                // == g1 + 1
    float iy = fmaf(ay, 32.0f, -0.5f);
    float x0f = floorf(ix), y0f = floorf(iy);
    float wx1 = ix - x0f, wy1 = iy - y0f;
    float wx0 = 1.0f - wx1, wy0 = 1.0f - wy1;
    int x0 = (int)x0f, y0 = (int)y0f;    // x0 in [-1,63]; y0 unbounded
    bool vx0 = x0 >= 0;
    bool vx1 = x0 < WW - 1;
    bool vy0 = (y0 >= 0) & (y0 < HH);
    bool vy1 = (y0 >= -1) & (y0 < HH - 1);
    float w00 = (vx0 && vy0) ? wx0 * wy0 : 0.0f;
    float w10 = (vx1 && vy0) ? wx1 * wy0 : 0.0f;
    float w01 = (vx0 && vy1) ? wx0 * wy1 : 0.0f;
    float w11 = (vx1 && vy1) ? wx1 * wy1 : 0.0f;
    bool lo1 = x0 < 0;                   // x0=-1: rec slot A is column 0
    float wA0 = lo1 ? w10 : w00, wB0 = lo1 ? 0.0f : w10;
    float wA1 = lo1 ? w11 : w01, wB1 = lo1 ? 0.0f : w11;
    uint32_t h0 = pkh2(wA0, wB0);
    uint32_t h1 = pkh2(wA1, wB1);
    bool swy = y0 < 0;                   // y0=-1: rec top row is row 0
    htop = swy ? h1 : h0;
    hbot = swy ? 0u : h1;
    int xa = max(x0, 0);
    int ya = min(max(y0, 0), HH - 1);
    off = ya * 64 + xa;
}

__device__ __forceinline__ void dot4(uint4 q, uint32_t htop, uint32_t hbot,
                                     float& acc0, float& acc1) {
    acc0 = fdot2f(q.x, htop, acc0);
    acc1 = fdot2f(q.y, htop, acc1);
    acc0 = fdot2f(q.z, hbot, acc0);
    acc1 = fdot2f(q.w, hbot, acc1);
}

// ---------------------------------------------------------------------------
// Main kernel: block = (cg,b,tl,yq) decoded from blockIdx ONLY (plane bases
// provably wave-uniform -> SGPR addressing); thread = (ysub,x). Handles
// t_lo = tl and t_hi = 31-tl (33 samples). One 16B gather per sample.
// Branch-free two-loop structure (r11). Grid = 2048 blocks, 8 blocks/CU.
// ---------------------------------------------------------------------------
__global__ __launch_bounds__(256, 8) void warp_pscan_v12(
    const float* __restrict__ cum, const uint32_t* __restrict__ planes,
    float* __restrict__ out) {
    int blk = blockIdx.x;   // 2048 = yq(16) | tl(16) | b(2) | cg(4)
    int tid = threadIdx.x;
    int yq = blk & 15;
    int tl = (blk >> 4) & 15;
    int b  = (blk >> 8) & 1;
    int cg = blk >> 9;
    int x  = tid & 63;
    int t_lo = tl, t_hi = (LL - 1) - tl;
    int pix = yq * 256 + tid;  // y = yq*4 + (tid>>6)

    float gx = -1.0f + (float)(2 * x + 1) * (1.0f / WW);
    int y = pix >> 6;
    float gy = -1.0f + (float)(2 * y + 1) * (1.0f / HH);

    const float* cumb = cum + (size_t)b * LL * 2 * HWL + pix;
    float ctxlo = cumb[(size_t)(2 * t_lo) * HWL];
    float ctylo = cumb[(size_t)(2 * t_lo + 1) * HWL];
    float ctxhi = cumb[(size_t)(2 * t_hi) * HWL];
    float ctyhi = cumb[(size_t)(2 * t_hi + 1) * HWL];

    float gx1 = gx + 1.0f, gy1 = gy + 1.0f;
    float axl = gx1 + ctxlo, ayl = gy1 + ctylo;
    float axh = gx1 + ctxhi, ayh = gy1 + ctyhi;

    float a0l = 0.0f, a1l = 0.0f, a0h = 0.0f, a1h = 0.0f;

    const uint4* plb =
        reinterpret_cast<const uint4*>(planes) + (size_t)(b * LL * 4 + cg) * 4096;
    const size_t KS = 4 * 4096;  // uint4 recs per k-step

    int k = 0;
    // ---- Loop A: k-pairs, both t_lo and t_hi ------------------------------
    for (; k + 1 <= t_lo; k += 2) {
        float cx0 = cumb[(size_t)(2 * k) * HWL];
        float cy0 = cumb[(size_t)(2 * k + 1) * HWL];
        float cx1 = cumb[(size_t)(2 * k + 2) * HWL];
        float cy1 = cumb[(size_t)(2 * k + 3) * HWL];
        const uint4* r0 = plb + (size_t)k * KS;
        const uint4* r1 = r0 + KS;
        int oh0, ol0, oh1, ol1;
        uint32_t th0, bh0, tl0, bl0, th1, bh1, tl1, bl1;
        prep_s2(axh, ayh, cx0, cy0, oh0, th0, bh0);
        prep_s2(axl, ayl, cx0, cy0, ol0, tl0, bl0);
        prep_s2(axh, ayh, cx1, cy1, oh1, th1, bh1);
        prep_s2(axl, ayl, cx1, cy1, ol1, tl1, bl1);
        uint4 qh0 = r0[oh0], ql0 = r0[ol0];
        uint4 qh1 = r1[oh1], ql1 = r1[ol1];
        dot4(qh0, th0, bh0, a0h, a1h);
        dot4(ql0, tl0, bl0, a0l, a1l);
        dot4(qh1, th1, bh1, a0h, a1h);
        dot4(ql1, tl1, bl1, a0l, a1l);
    }
    if (k <= t_lo) {  // loop-A tail
        float cx0 = cumb[(size_t)(2 * k) * HWL];
        float cy0 = cumb[(size_t)(2 * k + 1) * HWL];
        const uint4* r0 = plb + (size_t)k * KS;
        int oh0, ol0;
        uint32_t th0, bh0, tl0, bl0;
        prep_s2(axh, ayh, cx0, cy0, oh0, th0, bh0);
        prep_s2(axl, ayl, cx0, cy0, ol0, tl0, bl0);
        uint4 qh0 = r0[oh0], ql0 = r0[ol0];
        dot4(qh0, th0, bh0, a0h, a1h);
        dot4(ql0, tl0, bl0, a0l, a1l);
        ++k;
    }
    // ---- Loop B: k-quads, hi only ------------------------------------------
    for (; k + 3 <= t_hi; k += 4) {
        float cx0 = cumb[(size_t)(2 * k) * HWL];
        float cy0 = cumb[(size_t)(2 * k + 1) * HWL];
        float cx1 = cumb[(size_t)(2 * k + 2) * HWL];
        float cy1 = cumb[(size_t)(2 * k + 3) * HWL];
        float cx2 = cumb[(size_t)(2 * k + 4) * HWL];
        float cy2 = cumb[(size_t)(2 * k + 5) * HWL];
        float cx3 = cumb[(size_t)(2 * k + 6) * HWL];
        float cy3 = cumb[(size_t)(2 * k + 7) * HWL];
        const uint4* r0 = plb + (size_t)k * KS;
        const uint4* r1 = r0 + KS;
        const uint4* r2 = r1 + KS;
        const uint4* r3 = r2 + KS;
        int o0, o1, o2, o3;
        uint32_t t0, b0, t1, b1, t2, b2, t3, b3;
        prep_s2(axh, ayh, cx0, cy0, o0, t0, b0);
        prep_s2(axh, ayh, cx1, cy1, o1, t1, b1);
        prep_s2(axh, ayh, cx2, cy2, o2, t2, b2);
        prep_s2(axh, ayh, cx3, cy3, o3, t3, b3);
        uint4 q0 = r0[o0], q1 = r1[o1], q2 = r2[o2], q3 = r3[o3];
        dot4(q0, t0, b0, a0h, a1h);
        dot4(q1, t1, b1, a0h, a1h);
        dot4(q2, t2, b2, a0h, a1h);
        dot4(q3, t3, b3, a0h, a1h);
    }
    for (; k <= t_hi; ++k) {  // loop-B tail
        float cx = cumb[(size_t)(2 * k) * HWL];
        float cy = cumb[(size_t)(2 * k + 1) * HWL];
        const uint4* r0 = plb + (size_t)k * KS;
        int o0;
        uint32_t t0, b0;
        prep_s2(axh, ayh, cx, cy, o0, t0, b0);
        uint4 q0 = r0[o0];
        dot4(q0, t0, b0, a0h, a1h);
    }

    int c0 = cg * 2;
    float* ol = out + ((size_t)(b * LL + t_lo) * CC + c0) * HWL + pix;
    ol[0]   = a0l;
    ol[HWL] = a1l;
    float* oh = out + ((size_t)(b * LL + t_hi) * CC + c0) * HWL + pix;
    oh[0]   = a0h;
    oh[HWL] = a1h;
}

// ---------------------------------------------------------------------------
// Fallback (ws too small): fp32 scalar path, original layouts (r5-proven).
// ---------------------------------------------------------------------------
__global__ __launch_bounds__(256) void warp_pscan_fb(
    const float* __restrict__ cum, const float* __restrict__ images,
    float* __restrict__ out) {
    int idx = blockIdx.x * blockDim.x + threadIdx.x;
    if (idx >= BB * LL * HWL) return;
    int x  = idx & (WW - 1);
    int y  = (idx >> 6) & (HH - 1);
    int tl = (idx >> 12) & (LL - 1);
    int b  = idx >> 17;
    int t = (tl < 16) ? tl : (47 - tl);
    int pix = y * WW + x;
    float gx = -1.0f + (float)(2 * x + 1) * (1.0f / WW);
    float gy = -1.0f + (float)(2 * y + 1) * (1.0f / HH);
    const float* cumb = cum + (size_t)b * LL * 2 * HWL + pix;
    float ctx = cumb[(size_t)(2 * t) * HWL];
    float cty = cumb[(size_t)(2 * t + 1) * HWL];
    float acc[CC];
#pragma unroll
    for (int c = 0; c < CC; ++c) acc[c] = 0.0f;
    const float* imgb = images + (size_t)b * LL * CC * HWL;
    for (int k = 0; k <= t; ++k) {
        float dx = ctx - cumb[(size_t)(2 * k) * HWL];
        float dy = cty - cumb[(size_t)(2 * k + 1) * HWL];
        float g0 = gx + dx, g1 = gy + dy;
        float a = g0 + 1.0f, h = a * 0.5f;
        float rem = (h - floorf(h)) * 2.0f;
        float ix = fmaf(rem, 32.0f, -0.5f);
        float iy = fmaf(g1 + 1.0f, 32.0f, -0.5f);
        float x0f = floorf(ix), y0f = floorf(iy);
        float wx1 = ix - x0f, wy1 = iy - y0f;
        float wx0 = 1.0f - wx1, wy0 = 1.0f - wy1;
        int x0 = (int)x0f, y0 = (int)y0f;
        bool vx0 = x0 >= 0, vx1 = x0 < WW - 1;
        bool vy0 = (y0 >= 0) & (y0 < HH), vy1 = (y0 >= -1) & (y0 < HH - 1);
        int x0c = max(x0, 0), x1c = min(x0 + 1, WW - 1);
        int y0c = min(max(y0, 0), HH - 1), y1c = min(max(y0 + 1, 0), HH - 1);
        float w00 = (vx0 && vy0) ? wx0 * wy0 : 0.0f;
        float w10 = (vx1 && vy0) ? wx1 * wy0 : 0.0f;
        float w01 = (vx0 && vy1) ? wx0 * wy1 : 0.0f;
        float w11 = (vx1 && vy1) ? wx1 * wy1 : 0.0f;
        int o00 = y0c * WW + x0c, o10 = y0c * WW + x1c;
        int o01 = y1c * WW + x0c, o11 = y1c * WW + x1c;
        const float* ip = imgb + (size_t)k * CC * HWL;
#pragma unroll
        for (int c = 0; c < CC; ++c) {
            const float* ic = ip + (size_t)c * HWL;
            acc[c] += w00 * ic[o00] + w10 * ic[o10] + w01 * ic[o01] +
                      w11 * ic[o11];
        }
    }
    float* op = out + ((size_t)(b * LL + t) * CC) * HWL + pix;
#pragma unroll
    for (int c = 0; c < CC; ++c) op[(size_t)c * HWL] = acc[c];
}

extern "C" void kernel_launch(void* const* d_in, const int* in_sizes, int n_in,
                              void* d_out, int out_size, void* d_ws,
                              size_t ws_size, hipStream_t stream) {
    const float* flows  = (const float*)d_in[0];
    const float* images = (const float*)d_in[1];
    float* out = (float*)d_out;

    const size_t cum_bytes   = (size_t)BB * LL * 2 * HWL * sizeof(float);  // 2 MiB
    const size_t plane_bytes = (size_t)BB * LL * 4 * 4096 * 16;            // 16 MiB
    float* cum       = (float*)d_ws;
    uint32_t* planes = (uint32_t*)((char*)d_ws + cum_bytes);
    bool full = (ws_size >= cum_bytes + plane_bytes);

    if (full) {
        int nprep = CUM_BLOCKS + (BB * LL * HH * 32) / 256;  // 64 + 512 = 576
        prep_kernel<<<nprep, 256, 0, stream>>>(flows, images, cum, planes);
        warp_pscan_v12<<<2048, 256, 0, stream>>>(cum, planes, out);
    } else {
        prep_kernel<<<CUM_BLOCKS, 256, 0, stream>>>(flows, images, cum,
                                                    planes);
        int n3 = BB * LL * HWL;
        warp_pscan_fb<<<(n3 + 255) / 256, 256, 0, stream>>>(cum, images, out);
    }
}

// Round 13
// 55.917 us; speedup vs baseline: 1.1891x; 1.1891x over previous
//
#include <hip/hip_runtime.h>

// Problem constants: B=2, L=32, C=8, H=W=64
#define BB 2
#define LL 32
#define CC 8
#define HH 64
#define WW 64
#define HWL 4096

typedef _Float16 h2 __attribute__((ext_vector_type(2)));

#if defined(__has_builtin)
#if __has_builtin(__builtin_amdgcn_fdot2)
#define HAVE_FDOT2 1
#endif
#endif

__device__ __forceinline__ float fdot2f(uint32_t a, uint32_t b, float c) {
    union { uint32_t u; h2 h; } ua, ub;
    ua.u = a;
    ub.u = b;
#ifdef HAVE_FDOT2
    return __builtin_amdgcn_fdot2(ua.h, ub.h, c, false);
#else
    return c + (float)ua.h.x * (float)ub.h.x + (float)ua.h.y * (float)ub.h.y;
#endif
}

__device__ __forceinline__ uint32_t pkh2(float lo, float hi) {
    union { h2 h; uint32_t u; } v;
    v.h.x = (_Float16)lo;
    v.h.y = (_Float16)hi;
    return v.u;
}

// ---------------------------------------------------------------------------
// Fused prep kernel (r12-proven).
// Blocks [0,64): flow cumsum over B*2*H*W = 16384 threads.
// Blocks [64,576): build 2x2-pixel x 2-channel 16B records (r12 layout):
//   plane p = (b*LL+l)*4 + cg; rec(ya,xa) = uint4 covering rows {ya,ya+1},
//   cols {xa,xa+1}, channels {2cg,2cg+1}; col/row 64 = 0 pad.
// ---------------------------------------------------------------------------
#define CUM_BLOCKS 64

__global__ __launch_bounds__(256) void prep_kernel(
    const float* __restrict__ flows, const float* __restrict__ img,
    float* __restrict__ cum, uint32_t* __restrict__ planes) {
    int bid = blockIdx.x;
    if (bid < CUM_BLOCKS) {
        int idx  = bid * 256 + threadIdx.x;  // over B*2*H*W = 16384
        if (idx >= BB * 2 * HWL) return;
        int pix  = idx & (HWL - 1);
        int rest = idx >> 12;  // b*2 + comp, in [0,4)
        int comp = rest & 1;
        int b    = rest >> 1;
        size_t base = ((size_t)(b * LL) * 2 + comp) * HWL + pix;
        float v[LL];
#pragma unroll
        for (int l = 0; l < LL; ++l) v[l] = flows[base + (size_t)l * 2 * HWL];
        float acc = 0.0f;
#pragma unroll
        for (int l = 0; l < LL; ++l) {
            acc += v[l];
            cum[base + (size_t)l * 2 * HWL] = acc;
        }
    } else {
        int idx = (bid - CUM_BLOCKS) * 256 + threadIdx.x;  // over 64*64*32
        if (idx >= BB * LL * HH * 32) return;
        int r  = idx & 31;         // xa pair {2r, 2r+1}
        int ya = (idx >> 5) & 63;
        int bl = idx >> 11;        // b*32 + l, in [0,64)
        bool lastx = (r == 31);
        bool lasty = (ya == 63);
        const float* ip = img + (size_t)bl * CC * HWL + ya * WW + 2 * r;
        float t0[8], t1[8], t2[8], u0[8], u1[8], u2[8];
#pragma unroll
        for (int c = 0; c < 8; ++c) {
            const float* rp = ip + (size_t)c * HWL;
            float2 A = *reinterpret_cast<const float2*>(rp);
            t0[c] = A.x;
            t1[c] = A.y;
            t2[c] = lastx ? 0.0f : rp[2];
            if (!lasty) {
                float2 Bv = *reinterpret_cast<const float2*>(rp + WW);
                u0[c] = Bv.x;
                u1[c] = Bv.y;
                u2[c] = lastx ? 0.0f : rp[WW + 2];
            } else {
                u0[c] = 0.0f;
                u1[c] = 0.0f;
                u2[c] = 0.0f;
            }
        }
        uint4* P = reinterpret_cast<uint4*>(planes);
#pragma unroll
        for (int cg = 0; cg < 4; ++cg) {
            int c0 = 2 * cg, c1 = 2 * cg + 1;
            uint4 e, o;  // recs xa = 2r (even) and 2r+1 (odd)
            e.x = pkh2(t0[c0], t1[c0]);
            e.y = pkh2(t0[c1], t1[c1]);
            e.z = pkh2(u0[c0], u1[c0]);
            e.w = pkh2(u0[c1], u1[c1]);
            o.x = pkh2(t1[c0], t2[c0]);
            o.y = pkh2(t1[c1], t2[c1]);
            o.z = pkh2(u1[c0], u2[c0]);
            o.w = pkh2(u1[c1], u2[c1]);
            size_t base = (size_t)(bl * 4 + cg) * 4096 + ya * 64 + 2 * r;
            P[base]     = e;
            P[base + 1] = o;
        }
    }
}

// ---------------------------------------------------------------------------
// prep_s2 (r12-proven): grid math -> one record offset + packed top/bottom
// row weights. Weight values identical to rounds 3-12.
// ---------------------------------------------------------------------------
__device__ __forceinline__ void prep_s2(float axv, float ayv, float ckx,
                                        float cky, int& off, uint32_t& htop,
                                        uint32_t& hbot) {
    float aa = axv - ckx;                // == g0 + 1 (±1ulp reassoc)
    float hh = aa * 0.5f;
    float fh = floorf(hh);
    float tt = fmaf(fh, -64.0f, -0.5f);  // exact
    float ix = fmaf(aa, 32.0f, tt);      // in [-0.5, 63.5)
    float ay = ayv - cky;                // == g1 + 1
    float iy = fmaf(ay, 32.0f, -0.5f);
    float x0f = floorf(ix), y0f = floorf(iy);
    float wx1 = ix - x0f, wy1 = iy - y0f;
    float wx0 = 1.0f - wx1, wy0 = 1.0f - wy1;
    int x0 = (int)x0f, y0 = (int)y0f;    // x0 in [-1,63]
    bool vx0 = x0 >= 0;
    bool vx1 = x0 < WW - 1;
    bool vy0 = (y0 >= 0) & (y0 < HH);
    bool vy1 = (y0 >= -1) & (y0 < HH - 1);
    float w00 = (vx0 && vy0) ? wx0 * wy0 : 0.0f;
    float w10 = (vx1 && vy0) ? wx1 * wy0 : 0.0f;
    float w01 = (vx0 && vy1) ? wx0 * wy1 : 0.0f;
    float w11 = (vx1 && vy1) ? wx1 * wy1 : 0.0f;
    bool lo1 = x0 < 0;                   // x0=-1: rec slot A is column 0
    float wA0 = lo1 ? w10 : w00, wB0 = lo1 ? 0.0f : w10;
    float wA1 = lo1 ? w11 : w01, wB1 = lo1 ? 0.0f : w11;
    uint32_t h0 = pkh2(wA0, wB0);
    uint32_t h1 = pkh2(wA1, wB1);
    bool swy = y0 < 0;                   // y0=-1: rec top row is row 0
    htop = swy ? h1 : h0;
    hbot = swy ? 0u : h1;
    int xa = max(x0, 0);
    int ya = min(max(y0, 0), HH - 1);
    off = ya * 64 + xa;
}

__device__ __forceinline__ void dot4(uint4 q, uint32_t htop, uint32_t hbot,
                                     float& acc0, float& acc1) {
    acc0 = fdot2f(q.x, htop, acc0);
    acc1 = fdot2f(q.y, htop, acc1);
    acc0 = fdot2f(q.z, hbot, acc0);
    acc1 = fdot2f(q.w, hbot, acc1);
}

// ---------------------------------------------------------------------------
// Main kernel (v13): identical to v12 EXCEPT the block-index mapping is
// XCD-aware: blk = rest*8 + (b*4 + cg). Workgroups round-robin across the
// 8 XCDs, so all blocks sharing plane-slice (b,cg) (2 MB) land on ONE XCD
// -> slice is L2-resident (4 MB/XCD) instead of L3-latency misses.
// ---------------------------------------------------------------------------
__global__ __launch_bounds__(256, 8) void warp_pscan_v13(
    const float* __restrict__ cum, const uint32_t* __restrict__ planes,
    float* __restrict__ out) {
    int blk = blockIdx.x;   // 2048 = rest(256) * 8 + xcd(8)
    int tid = threadIdx.x;
    int xcd  = blk & 7;
    int rest = blk >> 3;
    int cg = xcd & 3;
    int b  = xcd >> 2;
    int yq = rest & 15;
    int tl = rest >> 4;     // in [0,16)
    int x  = tid & 63;
    int t_lo = tl, t_hi = (LL - 1) - tl;
    int pix = yq * 256 + tid;  // y = yq*4 + (tid>>6)

    float gx = -1.0f + (float)(2 * x + 1) * (1.0f / WW);
    int y = pix >> 6;
    float gy = -1.0f + (float)(2 * y + 1) * (1.0f / HH);

    const float* cumb = cum + (size_t)b * LL * 2 * HWL + pix;
    float ctxlo = cumb[(size_t)(2 * t_lo) * HWL];
    float ctylo = cumb[(size_t)(2 * t_lo + 1) * HWL];
    float ctxhi = cumb[(size_t)(2 * t_hi) * HWL];
    float ctyhi = cumb[(size_t)(2 * t_hi + 1) * HWL];

    float gx1 = gx + 1.0f, gy1 = gy + 1.0f;
    float axl = gx1 + ctxlo, ayl = gy1 + ctylo;
    float axh = gx1 + ctxhi, ayh = gy1 + ctyhi;

    float a0l = 0.0f, a1l = 0.0f, a0h = 0.0f, a1h = 0.0f;

    const uint4* plb =
        reinterpret_cast<const uint4*>(planes) + (size_t)(b * LL * 4 + cg) * 4096;
    const size_t KS = 4 * 4096;  // uint4 recs per k-step

    int k = 0;
    // ---- Loop A: k-pairs, both t_lo and t_hi ------------------------------
    for (; k + 1 <= t_lo; k += 2) {
        float cx0 = cumb[(size_t)(2 * k) * HWL];
        float cy0 = cumb[(size_t)(2 * k + 1) * HWL];
        float cx1 = cumb[(size_t)(2 * k + 2) * HWL];
        float cy1 = cumb[(size_t)(2 * k + 3) * HWL];
        const uint4* r0 = plb + (size_t)k * KS;
        const uint4* r1 = r0 + KS;
        int oh0, ol0, oh1, ol1;
        uint32_t th0, bh0, tl0, bl0, th1, bh1, tl1, bl1;
        prep_s2(axh, ayh, cx0, cy0, oh0, th0, bh0);
        prep_s2(axl, ayl, cx0, cy0, ol0, tl0, bl0);
        prep_s2(axh, ayh, cx1, cy1, oh1, th1, bh1);
        prep_s2(axl, ayl, cx1, cy1, ol1, tl1, bl1);
        uint4 qh0 = r0[oh0], ql0 = r0[ol0];
        uint4 qh1 = r1[oh1], ql1 = r1[ol1];
        dot4(qh0, th0, bh0, a0h, a1h);
        dot4(ql0, tl0, bl0, a0l, a1l);
        dot4(qh1, th1, bh1, a0h, a1h);
        dot4(ql1, tl1, bl1, a0l, a1l);
    }
    if (k <= t_lo) {  // loop-A tail
        float cx0 = cumb[(size_t)(2 * k) * HWL];
        float cy0 = cumb[(size_t)(2 * k + 1) * HWL];
        const uint4* r0 = plb + (size_t)k * KS;
        int oh0, ol0;
        uint32_t th0, bh0, tl0, bl0;
        prep_s2(axh, ayh, cx0, cy0, oh0, th0, bh0);
        prep_s2(axl, ayl, cx0, cy0, ol0, tl0, bl0);
        uint4 qh0 = r0[oh0], ql0 = r0[ol0];
        dot4(qh0, th0, bh0, a0h, a1h);
        dot4(ql0, tl0, bl0, a0l, a1l);
        ++k;
    }
    // ---- Loop B: k-quads, hi only ------------------------------------------
    for (; k + 3 <= t_hi; k += 4) {
        float cx0 = cumb[(size_t)(2 * k) * HWL];
        float cy0 = cumb[(size_t)(2 * k + 1) * HWL];
        float cx1 = cumb[(size_t)(2 * k + 2) * HWL];
        float cy1 = cumb[(size_t)(2 * k + 3) * HWL];
        float cx2 = cumb[(size_t)(2 * k + 4) * HWL];
        float cy2 = cumb[(size_t)(2 * k + 5) * HWL];
        float cx3 = cumb[(size_t)(2 * k + 6) * HWL];
        float cy3 = cumb[(size_t)(2 * k + 7) * HWL];
        const uint4* r0 = plb + (size_t)k * KS;
        const uint4* r1 = r0 + KS;
        const uint4* r2 = r1 + KS;
        const uint4* r3 = r2 + KS;
        int o0, o1, o2, o3;
        uint32_t t0, b0, t1, b1, t2, b2, t3, b3;
        prep_s2(axh, ayh, cx0, cy0, o0, t0, b0);
        prep_s2(axh, ayh, cx1, cy1, o1, t1, b1);
        prep_s2(axh, ayh, cx2, cy2, o2, t2, b2);
        prep_s2(axh, ayh, cx3, cy3, o3, t3, b3);
        uint4 q0 = r0[o0], q1 = r1[o1], q2 = r2[o2], q3 = r3[o3];
        dot4(q0, t0, b0, a0h, a1h);
        dot4(q1, t1, b1, a0h, a1h);
        dot4(q2, t2, b2, a0h, a1h);
        dot4(q3, t3, b3, a0h, a1h);
    }
    for (; k <= t_hi; ++k) {  // loop-B tail
        float cx = cumb[(size_t)(2 * k) * HWL];
        float cy = cumb[(size_t)(2 * k + 1) * HWL];
        const uint4* r0 = plb + (size_t)k * KS;
        int o0;
        uint32_t t0, b0;
        prep_s2(axh, ayh, cx, cy, o0, t0, b0);
        uint4 q0 = r0[o0];
        dot4(q0, t0, b0, a0h, a1h);
    }

    int c0 = cg * 2;
    float* ol = out + ((size_t)(b * LL + t_lo) * CC + c0) * HWL + pix;
    ol[0]   = a0l;
    ol[HWL] = a1l;
    float* oh = out + ((size_t)(b * LL + t_hi) * CC + c0) * HWL + pix;
    oh[0]   = a0h;
    oh[HWL] = a1h;
}

// ---------------------------------------------------------------------------
// Fallback (ws too small): fp32 scalar path, original layouts (r5-proven).
// ---------------------------------------------------------------------------
__global__ __launch_bounds__(256) void warp_pscan_fb(
    const float* __restrict__ cum, const float* __restrict__ images,
    float* __restrict__ out) {
    int idx = blockIdx.x * blockDim.x + threadIdx.x;
    if (idx >= BB * LL * HWL) return;
    int x  = idx & (WW - 1);
    int y  = (idx >> 6) & (HH - 1);
    int tl = (idx >> 12) & (LL - 1);
    int b  = idx >> 17;
    int t = (tl < 16) ? tl : (47 - tl);
    int pix = y * WW + x;
    float gx = -1.0f + (float)(2 * x + 1) * (1.0f / WW);
    float gy = -1.0f + (float)(2 * y + 1) * (1.0f / HH);
    const float* cumb = cum + (size_t)b * LL * 2 * HWL + pix;
    float ctx = cumb[(size_t)(2 * t) * HWL];
    float cty = cumb[(size_t)(2 * t + 1) * HWL];
    float acc[CC];
#pragma unroll
    for (int c = 0; c < CC; ++c) acc[c] = 0.0f;
    const float* imgb = images + (size_t)b * LL * CC * HWL;
    for (int k = 0; k <= t; ++k) {
        float dx = ctx - cumb[(size_t)(2 * k) * HWL];
        float dy = cty - cumb[(size_t)(2 * k + 1) * HWL];
        float g0 = gx + dx, g1 = gy + dy;
        float a = g0 + 1.0f, h = a * 0.5f;
        float rem = (h - floorf(h)) * 2.0f;
        float ix = fmaf(rem, 32.0f, -0.5f);
        float iy = fmaf(g1 + 1.0f, 32.0f, -0.5f);
        float x0f = floorf(ix), y0f = floorf(iy);
        float wx1 = ix - x0f, wy1 = iy - y0f;
        float wx0 = 1.0f - wx1, wy0 = 1.0f - wy1;
        int x0 = (int)x0f, y0 = (int)y0f;
        bool vx0 = x0 >= 0, vx1 = x0 < WW - 1;
        bool vy0 = (y0 >= 0) & (y0 < HH), vy1 = (y0 >= -1) & (y0 < HH - 1);
        int x0c = max(x0, 0), x1c = min(x0 + 1, WW - 1);
        int y0c = min(max(y0, 0), HH - 1), y1c = min(max(y0 + 1, 0), HH - 1);
        float w00 = (vx0 && vy0) ? wx0 * wy0 : 0.0f;
        float w10 = (vx1 && vy0) ? wx1 * wy0 : 0.0f;
        float w01 = (vx0 && vy1) ? wx0 * wy1 : 0.0f;
        float w11 = (vx1 && vy1) ? wx1 * wy1 : 0.0f;
        int o00 = y0c * WW + x0c, o10 = y0c * WW + x1c;
        int o01 = y1c * WW + x0c, o11 = y1c * WW + x1c;
        const float* ip = imgb + (size_t)k * CC * HWL;
#pragma unroll
        for (int c = 0; c < CC; ++c) {
            const float* ic = ip + (size_t)c * HWL;
            acc[c] += w00 * ic[o00] + w10 * ic[o10] + w01 * ic[o01] +
                      w11 * ic[o11];
        }
    }
    float* op = out + ((size_t)(b * LL + t) * CC) * HWL + pix;
#pragma unroll
    for (int c = 0; c < CC; ++c) op[(size_t)c * HWL] = acc[c];
}

extern "C" void kernel_launch(void* const* d_in, const int* in_sizes, int n_in,
                              void* d_out, int out_size, void* d_ws,
                              size_t ws_size, hipStream_t stream) {
    const float* flows  = (const float*)d_in[0];
    const float* images = (const float*)d_in[1];
    float* out = (float*)d_out;

    const size_t cum_bytes   = (size_t)BB * LL * 2 * HWL * sizeof(float);  // 2 MiB
    const size_t plane_bytes = (size_t)BB * LL * 4 * 4096 * 16;            // 16 MiB
    float* cum       = (float*)d_ws;
    uint32_t* planes = (uint32_t*)((char*)d_ws + cum_bytes);
    bool full = (ws_size >= cum_bytes + plane_bytes);

    if (full) {
        int nprep = CUM_BLOCKS + (BB * LL * HH * 32) / 256;  // 64 + 512 = 576
        prep_kernel<<<nprep, 256, 0, stream>>>(flows, images, cum, planes);
        warp_pscan_v13<<<2048, 256, 0, stream>>>(cum, planes, out);
    } else {
        prep_kernel<<<CUM_BLOCKS, 256, 0, stream>>>(flows, images, cum,
                                                    planes);
        int n3 = BB * LL * HWL;
        warp_pscan_fb<<<(n3 + 255) / 256, 256, 0, stream>>>(cum, images, out);
    }
}

// Round 14
// 49.176 us; speedup vs baseline: 1.3521x; 1.1371x over previous
//
#include <hip/hip_runtime.h>

// Problem constants: B=2, L=32, C=8, H=W=64
#define BB 2
#define LL 32
#define CC 8
#define HH 64
#define WW 64
#define HWL 4096

typedef _Float16 h2 __attribute__((ext_vector_type(2)));

#if defined(__has_builtin)
#if __has_builtin(__builtin_amdgcn_fdot2)
#define HAVE_FDOT2 1
#endif
#endif

__device__ __forceinline__ float fdot2f(uint32_t a, uint32_t b, float c) {
    union { uint32_t u; h2 h; } ua, ub;
    ua.u = a;
    ub.u = b;
#ifdef HAVE_FDOT2
    return __builtin_amdgcn_fdot2(ua.h, ub.h, c, false);
#else
    return c + (float)ua.h.x * (float)ub.h.x + (float)ua.h.y * (float)ub.h.y;
#endif
}

__device__ __forceinline__ uint32_t pkh2(float lo, float hi) {
    union { h2 h; uint32_t u; } v;
    v.h.x = (_Float16)lo;
    v.h.y = (_Float16)hi;
    return v.u;
}

// ---------------------------------------------------------------------------
// Fused prep kernel, XCD-ALIGNED with the main kernel's reader mapping.
// Blocks [0,64): flow cumsum over B*2*H*W = 16384 threads (r10-proven).
// Blocks [64, 64+2048): repack. Block j = bid-64 handles plane-slice
//   slice = j & 7 = b*4+cg — the SAME slice-to-XCD key the main kernel
//   uses (main: blk&7 = b*4+cg). 64 cum blocks ≡ 0 (mod 8), so the
//   round-robin phase matches: writes land in the L2 that will read them.
//   Thread = (l, ya, r) for its fixed (b,cg); builds recs xa=2r, 2r+1.
//   Record layout (r12-proven): plane p=(b*LL+l)*4+cg; rec(ya,xa)=uint4
//   covering rows {ya,ya+1} x cols {xa,xa+1} x channels {2cg,2cg+1};
//   col/row 64 = 0 pad.
// ---------------------------------------------------------------------------
#define CUM_BLOCKS 64

__global__ __launch_bounds__(256) void prep_kernel(
    const float* __restrict__ flows, const float* __restrict__ img,
    float* __restrict__ cum, uint32_t* __restrict__ planes) {
    int bid = blockIdx.x;
    if (bid < CUM_BLOCKS) {
        int idx  = bid * 256 + threadIdx.x;  // over B*2*H*W = 16384
        if (idx >= BB * 2 * HWL) return;
        int pix  = idx & (HWL - 1);
        int rest = idx >> 12;  // b*2 + comp, in [0,4)
        int comp = rest & 1;
        int b    = rest >> 1;
        size_t base = ((size_t)(b * LL) * 2 + comp) * HWL + pix;
        float v[LL];
#pragma unroll
        for (int l = 0; l < LL; ++l) v[l] = flows[base + (size_t)l * 2 * HWL];
        float acc = 0.0f;
#pragma unroll
        for (int l = 0; l < LL; ++l) {
            acc += v[l];
            cum[base + (size_t)l * 2 * HWL] = acc;
        }
    } else {
        int j = bid - CUM_BLOCKS;        // 0..2047
        int slice = j & 7;               // = b*4 + cg (XCD key)
        int b  = slice >> 2;
        int cg = slice & 3;
        int idx = (j >> 3) * 256 + threadIdx.x;  // 0..65535 per slice
        int r  = idx & 31;               // xa pair {2r, 2r+1}
        int ya = (idx >> 5) & 63;
        int l  = idx >> 11;              // 0..31
        int bl = b * LL + l;
        bool lastx = (r == 31);
        bool lasty = (ya == 63);
        int c0 = 2 * cg, c1 = 2 * cg + 1;
        const float* p0 = img + ((size_t)bl * CC + c0) * HWL + ya * WW + 2 * r;
        const float* p1 = img + ((size_t)bl * CC + c1) * HWL + ya * WW + 2 * r;
        // rows ya (t*) and ya+1 (u*); 3 cols {2r, 2r+1, 2r+2}; 2 channels
        float2 A0 = *reinterpret_cast<const float2*>(p0);
        float2 A1 = *reinterpret_cast<const float2*>(p1);
        float t20 = lastx ? 0.0f : p0[2];
        float t21 = lastx ? 0.0f : p1[2];
        float u00 = 0.0f, u10 = 0.0f, u20 = 0.0f;
        float u01 = 0.0f, u11 = 0.0f, u21 = 0.0f;
        if (!lasty) {
            float2 B0 = *reinterpret_cast<const float2*>(p0 + WW);
            float2 B1 = *reinterpret_cast<const float2*>(p1 + WW);
            u00 = B0.x;
            u10 = B0.y;
            u20 = lastx ? 0.0f : p0[WW + 2];
            u01 = B1.x;
            u11 = B1.y;
            u21 = lastx ? 0.0f : p1[WW + 2];
        }
        uint4 e, o;  // recs xa = 2r (even) and 2r+1 (odd)
        e.x = pkh2(A0.x, A0.y);
        e.y = pkh2(A1.x, A1.y);
        e.z = pkh2(u00, u10);
        e.w = pkh2(u01, u11);
        o.x = pkh2(A0.y, t20);
        o.y = pkh2(A1.y, t21);
        o.z = pkh2(u10, u20);
        o.w = pkh2(u11, u21);
        uint4* P = reinterpret_cast<uint4*>(planes);
        size_t base = (size_t)(bl * 4 + cg) * 4096 + ya * 64 + 2 * r;
        P[base]     = e;
        P[base + 1] = o;
    }
}

// ---------------------------------------------------------------------------
// prep_s2 (r12-proven): grid math -> one record offset + packed top/bottom
// row weights. Weight values identical to rounds 3-13.
// ---------------------------------------------------------------------------
__device__ __forceinline__ void prep_s2(float axv, float ayv, float ckx,
                                        float cky, int& off, uint32_t& htop,
                                        uint32_t& hbot) {
    float aa = axv - ckx;                // == g0 + 1 (±1ulp reassoc)
    float hh = aa * 0.5f;
    float fh = floorf(hh);
    float tt = fmaf(fh, -64.0f, -0.5f);  // exact
    float ix = fmaf(aa, 32.0f, tt);      // in [-0.5, 63.5)
    float ay = ayv - cky;                // == g1 + 1
    float iy = fmaf(ay, 32.0f, -0.5f);
    float x0f = floorf(ix), y0f = floorf(iy);
    float wx1 = ix - x0f, wy1 = iy - y0f;
    float wx0 = 1.0f - wx1, wy0 = 1.0f - wy1;
    int x0 = (int)x0f, y0 = (int)y0f;    // x0 in [-1,63]
    bool vx0 = x0 >= 0;
    bool vx1 = x0 < WW - 1;
    bool vy0 = (y0 >= 0) & (y0 < HH);
    bool vy1 = (y0 >= -1) & (y0 < HH - 1);
    float w00 = (vx0 && vy0) ? wx0 * wy0 : 0.0f;
    float w10 = (vx1 && vy0) ? wx1 * wy0 : 0.0f;
    float w01 = (vx0 && vy1) ? wx0 * wy1 : 0.0f;
    float w11 = (vx1 && vy1) ? wx1 * wy1 : 0.0f;
    bool lo1 = x0 < 0;                   // x0=-1: rec slot A is column 0
    float wA0 = lo1 ? w10 : w00, wB0 = lo1 ? 0.0f : w10;
    float wA1 = lo1 ? w11 : w01, wB1 = lo1 ? 0.0f : w11;
    uint32_t h0 = pkh2(wA0, wB0);
    uint32_t h1 = pkh2(wA1, wB1);
    bool swy = y0 < 0;                   // y0=-1: rec top row is row 0
    htop = swy ? h1 : h0;
    hbot = swy ? 0u : h1;
    int xa = max(x0, 0);
    int ya = min(max(y0, 0), HH - 1);
    off = ya * 64 + xa;
}

__device__ __forceinline__ void dot4(uint4 q, uint32_t htop, uint32_t hbot,
                                     float& acc0, float& acc1) {
    acc0 = fdot2f(q.x, htop, acc0);
    acc1 = fdot2f(q.y, htop, acc1);
    acc0 = fdot2f(q.z, hbot, acc0);
    acc1 = fdot2f(q.w, hbot, acc1);
}

// ---------------------------------------------------------------------------
// Main kernel (v13-proven, unchanged): XCD-aware mapping blk&7 = b*4+cg.
// ---------------------------------------------------------------------------
__global__ __launch_bounds__(256, 8) void warp_pscan_v14(
    const float* __restrict__ cum, const uint32_t* __restrict__ planes,
    float* __restrict__ out) {
    int blk = blockIdx.x;   // 2048 = rest(256) * 8 + xcd(8)
    int tid = threadIdx.x;
    int xcd  = blk & 7;
    int rest = blk >> 3;
    int cg = xcd & 3;
    int b  = xcd >> 2;
    int yq = rest & 15;
    int tl = rest >> 4;     // in [0,16)
    int x  = tid & 63;
    int t_lo = tl, t_hi = (LL - 1) - tl;
    int pix = yq * 256 + tid;  // y = yq*4 + (tid>>6)

    float gx = -1.0f + (float)(2 * x + 1) * (1.0f / WW);
    int y = pix >> 6;
    float gy = -1.0f + (float)(2 * y + 1) * (1.0f / HH);

    const float* cumb = cum + (size_t)b * LL * 2 * HWL + pix;
    float ctxlo = cumb[(size_t)(2 * t_lo) * HWL];
    float ctylo = cumb[(size_t)(2 * t_lo + 1) * HWL];
    float ctxhi = cumb[(size_t)(2 * t_hi) * HWL];
    float ctyhi = cumb[(size_t)(2 * t_hi + 1) * HWL];

    float gx1 = gx + 1.0f, gy1 = gy + 1.0f;
    float axl = gx1 + ctxlo, ayl = gy1 + ctylo;
    float axh = gx1 + ctxhi, ayh = gy1 + ctyhi;

    float a0l = 0.0f, a1l = 0.0f, a0h = 0.0f, a1h = 0.0f;

    const uint4* plb =
        reinterpret_cast<const uint4*>(planes) + (size_t)(b * LL * 4 + cg) * 4096;
    const size_t KS = 4 * 4096;  // uint4 recs per k-step

    int k = 0;
    // ---- Loop A: k-pairs, both t_lo and t_hi ------------------------------
    for (; k + 1 <= t_lo; k += 2) {
        float cx0 = cumb[(size_t)(2 * k) * HWL];
        float cy0 = cumb[(size_t)(2 * k + 1) * HWL];
        float cx1 = cumb[(size_t)(2 * k + 2) * HWL];
        float cy1 = cumb[(size_t)(2 * k + 3) * HWL];
        const uint4* r0 = plb + (size_t)k * KS;
        const uint4* r1 = r0 + KS;
        int oh0, ol0, oh1, ol1;
        uint32_t th0, bh0, tl0, bl0, th1, bh1, tl1, bl1;
        prep_s2(axh, ayh, cx0, cy0, oh0, th0, bh0);
        prep_s2(axl, ayl, cx0, cy0, ol0, tl0, bl0);
        prep_s2(axh, ayh, cx1, cy1, oh1, th1, bh1);
        prep_s2(axl, ayl, cx1, cy1, ol1, tl1, bl1);
        uint4 qh0 = r0[oh0], ql0 = r0[ol0];
        uint4 qh1 = r1[oh1], ql1 = r1[ol1];
        dot4(qh0, th0, bh0, a0h, a1h);
        dot4(ql0, tl0, bl0, a0l, a1l);
        dot4(qh1, th1, bh1, a0h, a1h);
        dot4(ql1, tl1, bl1, a0l, a1l);
    }
    if (k <= t_lo) {  // loop-A tail
        float cx0 = cumb[(size_t)(2 * k) * HWL];
        float cy0 = cumb[(size_t)(2 * k + 1) * HWL];
        const uint4* r0 = plb + (size_t)k * KS;
        int oh0, ol0;
        uint32_t th0, bh0, tl0, bl0;
        prep_s2(axh, ayh, cx0, cy0, oh0, th0, bh0);
        prep_s2(axl, ayl, cx0, cy0, ol0, tl0, bl0);
        uint4 qh0 = r0[oh0], ql0 = r0[ol0];
        dot4(qh0, th0, bh0, a0h, a1h);
        dot4(ql0, tl0, bl0, a0l, a1l);
        ++k;
    }
    // ---- Loop B: k-quads, hi only ------------------------------------------
    for (; k + 3 <= t_hi; k += 4) {
        float cx0 = cumb[(size_t)(2 * k) * HWL];
        float cy0 = cumb[(size_t)(2 * k + 1) * HWL];
        float cx1 = cumb[(size_t)(2 * k + 2) * HWL];
        float cy1 = cumb[(size_t)(2 * k + 3) * HWL];
        float cx2 = cumb[(size_t)(2 * k + 4) * HWL];
        float cy2 = cumb[(size_t)(2 * k + 5) * HWL];
        float cx3 = cumb[(size_t)(2 * k + 6) * HWL];
        float cy3 = cumb[(size_t)(2 * k + 7) * HWL];
        const uint4* r0 = plb + (size_t)k * KS;
        const uint4* r1 = r0 + KS;
        const uint4* r2 = r1 + KS;
        const uint4* r3 = r2 + KS;
        int o0, o1, o2, o3;
        uint32_t t0, b0, t1, b1, t2, b2, t3, b3;
        prep_s2(axh, ayh, cx0, cy0, o0, t0, b0);
        prep_s2(axh, ayh, cx1, cy1, o1, t1, b1);
        prep_s2(axh, ayh, cx2, cy2, o2, t2, b2);
        prep_s2(axh, ayh, cx3, cy3, o3, t3, b3);
        uint4 q0 = r0[o0], q1 = r1[o1], q2 = r2[o2], q3 = r3[o3];
        dot4(q0, t0, b0, a0h, a1h);
        dot4(q1, t1, b1, a0h, a1h);
        dot4(q2, t2, b2, a0h, a1h);
        dot4(q3, t3, b3, a0h, a1h);
    }
    for (; k <= t_hi; ++k) {  // loop-B tail
        float cx = cumb[(size_t)(2 * k) * HWL];
        float cy = cumb[(size_t)(2 * k + 1) * HWL];
        const uint4* r0 = plb + (size_t)k * KS;
        int o0;
        uint32_t t0, b0;
        prep_s2(axh, ayh, cx, cy, o0, t0, b0);
        uint4 q0 = r0[o0];
        dot4(q0, t0, b0, a0h, a1h);
    }

    int c0 = cg * 2;
    float* ol = out + ((size_t)(b * LL + t_lo) * CC + c0) * HWL + pix;
    ol[0]   = a0l;
    ol[HWL] = a1l;
    float* oh = out + ((size_t)(b * LL + t_hi) * CC + c0) * HWL + pix;
    oh[0]   = a0h;
    oh[HWL] = a1h;
}

// ---------------------------------------------------------------------------
// Fallback (ws too small): fp32 scalar path, original layouts (r5-proven).
// ---------------------------------------------------------------------------
__global__ __launch_bounds__(256) void warp_pscan_fb(
    const float* __restrict__ cum, const float* __restrict__ images,
    float* __restrict__ out) {
    int idx = blockIdx.x * blockDim.x + threadIdx.x;
    if (idx >= BB * LL * HWL) return;
    int x  = idx & (WW - 1);
    int y  = (idx >> 6) & (HH - 1);
    int tl = (idx >> 12) & (LL - 1);
    int b  = idx >> 17;
    int t = (tl < 16) ? tl : (47 - tl);
    int pix = y * WW + x;
    float gx = -1.0f + (float)(2 * x + 1) * (1.0f / WW);
    float gy = -1.0f + (float)(2 * y + 1) * (1.0f / HH);
    const float* cumb = cum + (size_t)b * LL * 2 * HWL + pix;
    float ctx = cumb[(size_t)(2 * t) * HWL];
    float cty = cumb[(size_t)(2 * t + 1) * HWL];
    float acc[CC];
#pragma unroll
    for (int c = 0; c < CC; ++c) acc[c] = 0.0f;
    const float* imgb = images + (size_t)b * LL * CC * HWL;
    for (int k = 0; k <= t; ++k) {
        float dx = ctx - cumb[(size_t)(2 * k) * HWL];
        float dy = cty - cumb[(size_t)(2 * k + 1) * HWL];
        float g0 = gx + dx, g1 = gy + dy;
        float a = g0 + 1.0f, h = a * 0.5f;
        float rem = (h - floorf(h)) * 2.0f;
        float ix = fmaf(rem, 32.0f, -0.5f);
        float iy = fmaf(g1 + 1.0f, 32.0f, -0.5f);
        float x0f = floorf(ix), y0f = floorf(iy);
        float wx1 = ix - x0f, wy1 = iy - y0f;
        float wx0 = 1.0f - wx1, wy0 = 1.0f - wy1;
        int x0 = (int)x0f, y0 = (int)y0f;
        bool vx0 = x0 >= 0, vx1 = x0 < WW - 1;
        bool vy0 = (y0 >= 0) & (y0 < HH), vy1 = (y0 >= -1) & (y0 < HH - 1);
        int x0c = max(x0, 0), x1c = min(x0 + 1, WW - 1);
        int y0c = min(max(y0, 0), HH - 1), y1c = min(max(y0 + 1, 0), HH - 1);
        float w00 = (vx0 && vy0) ? wx0 * wy0 : 0.0f;
        float w10 = (vx1 && vy0) ? wx1 * wy0 : 0.0f;
        float w01 = (vx0 && vy1) ? wx0 * wy1 : 0.0f;
        float w11 = (vx1 && vy1) ? wx1 * wy1 : 0.0f;
        int o00 = y0c * WW + x0c, o10 = y0c * WW + x1c;
        int o01 = y1c * WW + x0c, o11 = y1c * WW + x1c;
        const float* ip = imgb + (size_t)k * CC * HWL;
#pragma unroll
        for (int c = 0; c < CC; ++c) {
            const float* ic = ip + (size_t)c * HWL;
            acc[c] += w00 * ic[o00] + w10 * ic[o10] + w01 * ic[o01] +
                      w11 * ic[o11];
        }
    }
    float* op = out + ((size_t)(b * LL + t) * CC) * HWL + pix;
#pragma unroll
    for (int c = 0; c < CC; ++c) op[(size_t)c * HWL] = acc[c];
}

extern "C" void kernel_launch(void* const* d_in, const int* in_sizes, int n_in,
                              void* d_out, int out_size, void* d_ws,
                              size_t ws_size, hipStream_t stream) {
    const float* flows  = (const float*)d_in[0];
    const float* images = (const float*)d_in[1];
    float* out = (float*)d_out;

    const size_t cum_bytes   = (size_t)BB * LL * 2 * HWL * sizeof(float);  // 2 MiB
    const size_t plane_bytes = (size_t)BB * LL * 4 * 4096 * 16;            // 16 MiB
    float* cum       = (float*)d_ws;
    uint32_t* planes = (uint32_t*)((char*)d_ws + cum_bytes);
    bool full = (ws_size >= cum_bytes + plane_bytes);

    if (full) {
        int nprep = CUM_BLOCKS + 2048;  // 64 cum blocks + 2048 repack blocks
        prep_kernel<<<nprep, 256, 0, stream>>>(flows, images, cum, planes);
        warp_pscan_v14<<<2048, 256, 0, stream>>>(cum, planes, out);
    } else {
        prep_kernel<<<CUM_BLOCKS, 256, 0, stream>>>(flows, images, cum,
                                                    planes);
        int n3 = BB * LL * HWL;
        warp_pscan_fb<<<(n3 + 255) / 256, 256, 0, stream>>>(cum, images, out);
    }
}

// Round 15
// 36.368 us; speedup vs baseline: 1.8283x; 1.3522x over previous
//
#include <hip/hip_runtime.h>

// Problem constants: B=2, L=32, C=8, H=W=64
#define BB 2
#define LL 32
#define CC 8
#define HH 64
#define WW 64
#define HWL 4096

typedef _Float16 h2 __attribute__((ext_vector_type(2)));

#if defined(__has_builtin)
#if __has_builtin(__builtin_amdgcn_fdot2)
#define HAVE_FDOT2 1
#endif
#endif

__device__ __forceinline__ float fdot2f(uint32_t a, uint32_t b, float c) {
    union { uint32_t u; h2 h; } ua, ub;
    ua.u = a;
    ub.u = b;
#ifdef HAVE_FDOT2
    return __builtin_amdgcn_fdot2(ua.h, ub.h, c, false);
#else
    return c + (float)ua.h.x * (float)ub.h.x + (float)ua.h.y * (float)ub.h.y;
#endif
}

__device__ __forceinline__ uint32_t pkh2(float lo, float hi) {
    union { h2 h; uint32_t u; } v;
    v.h.x = (_Float16)lo;
    v.h.y = (_Float16)hi;
    return v.u;
}

// ---------------------------------------------------------------------------
// Record layout (v15): plane p = (b*LL + l)*2 + cg2, cg2 in {0,1} selects
// channels {4cg2..4cg2+3}. rec(y, xa) = uint4, word c = (px_xa.ch, px_xa+1.ch)
// for ch = 4cg2+c; xa in [0,64) (x-parity dup, col 64 -> 0 pad). A bilinear
// sample = 2 gathers (rows y0c, y1c) + 8 fdot2 covering 4 channels.
// Slices: (b,cg2) = 4 x 2 MB. XCD key = ((b*2+cg2)<<1) | y-half.
// ---------------------------------------------------------------------------
#define CUM_BLOCKS 64

__global__ __launch_bounds__(256) void prep_kernel(
    const float* __restrict__ flows, const float* __restrict__ img,
    float* __restrict__ cum, uint32_t* __restrict__ planes) {
    int bid = blockIdx.x;
    if (bid < CUM_BLOCKS) {
        int idx  = bid * 256 + threadIdx.x;  // over B*2*H*W = 16384
        if (idx >= BB * 2 * HWL) return;
        int pix  = idx & (HWL - 1);
        int rest = idx >> 12;  // b*2 + comp, in [0,4)
        int comp = rest & 1;
        int b    = rest >> 1;
        size_t base = ((size_t)(b * LL) * 2 + comp) * HWL + pix;
        float v[LL];
#pragma unroll
        for (int l = 0; l < LL; ++l) v[l] = flows[base + (size_t)l * 2 * HWL];
        float acc = 0.0f;
#pragma unroll
        for (int l = 0; l < LL; ++l) {
            acc += v[l];
            cum[base + (size_t)l * 2 * HWL] = acc;
        }
    } else {
        // Repack: block j, key = j&7 matches main's reader key (XCD-aligned
        // writes, r14-proven technique). Per key: 32 l x 32 y x 32 r.
        int j = bid - CUM_BLOCKS;  // [0,1024)
        int key = j & 7;
        int m = j >> 3;            // [0,128)
        int yhalf = key & 1;
        int bc = key >> 1;         // b*2 + cg2
        int cg2 = bc & 1;
        int b  = bc >> 1;
        int idx = m * 256 + threadIdx.x;  // [0, 32768)
        int r  = idx & 31;                // xa pair {2r, 2r+1}
        int yy = (idx >> 5) & 31;
        int l  = idx >> 10;               // [0,32)
        int y  = yhalf * 32 + yy;
        int bl = b * LL + l;
        int c0 = cg2 * 4;
        bool lastx = (r == 31);
        const float* ip = img + ((size_t)bl * CC + c0) * HWL + y * WW + 2 * r;
        float a0[4], a1[4], a2[4];
#pragma unroll
        for (int c = 0; c < 4; ++c) {
            const float* rp = ip + (size_t)c * HWL;
            float2 A = *reinterpret_cast<const float2*>(rp);
            a0[c] = A.x;
            a1[c] = A.y;
            a2[c] = lastx ? 0.0f : rp[2];
        }
        uint4 e, o;  // recs xa = 2r (even) and 2r+1 (odd)
        e.x = pkh2(a0[0], a1[0]);
        e.y = pkh2(a0[1], a1[1]);
        e.z = pkh2(a0[2], a1[2]);
        e.w = pkh2(a0[3], a1[3]);
        o.x = pkh2(a1[0], a2[0]);
        o.y = pkh2(a1[1], a2[1]);
        o.z = pkh2(a1[2], a2[2]);
        o.w = pkh2(a1[3], a2[3]);
        uint4* P = reinterpret_cast<uint4*>(planes);
        size_t base = ((size_t)(bl * 2 + cg2)) * 4096 + y * 64 + 2 * r;
        P[base]     = e;
        P[base + 1] = o;
    }
}

// ---------------------------------------------------------------------------
// prep_s3: grid math -> two row offsets + two packed column weights.
// Math identical to r8's proven sample2 (absmax 0.0625).
// ---------------------------------------------------------------------------
__device__ __forceinline__ void prep_s3(float axv, float ayv, float ckx,
                                        float cky, int& off0, int& off1,
                                        uint32_t& h0, uint32_t& h1) {
    float aa = axv - ckx;                // == g0 + 1 (±1ulp reassoc)
    float hh = aa * 0.5f;
    float fh = floorf(hh);
    float tt = fmaf(fh, -64.0f, -0.5f);  // exact
    float ix = fmaf(aa, 32.0f, tt);      // in [-0.5, 63.5)
    float ay = ayv - cky;                // == g1 + 1
    float iy = fmaf(ay, 32.0f, -0.5f);
    float x0f = floorf(ix), y0f = floorf(iy);
    float wx1 = ix - x0f, wy1 = iy - y0f;
    float wx0 = 1.0f - wx1, wy0 = 1.0f - wy1;
    int x0 = (int)x0f, y0 = (int)y0f;    // x0 in [-1,63]
    bool vx0 = x0 >= 0;
    bool vx1 = x0 < WW - 1;
    bool vy0 = (y0 >= 0) & (y0 < HH);
    bool vy1 = (y0 >= -1) & (y0 < HH - 1);
    float w00 = (vx0 && vy0) ? wx0 * wy0 : 0.0f;
    float w10 = (vx1 && vy0) ? wx1 * wy0 : 0.0f;
    float w01 = (vx0 && vy1) ? wx0 * wy1 : 0.0f;
    float w11 = (vx1 && vy1) ? wx1 * wy1 : 0.0f;
    bool lo1 = x0 < 0;                   // x0=-1: rec slot A is column 0
    float wA0 = lo1 ? w10 : w00, wB0 = lo1 ? 0.0f : w10;
    float wA1 = lo1 ? w11 : w01, wB1 = lo1 ? 0.0f : w11;
    int xa = max(x0, 0);
    int y0c = min(max(y0, 0), HH - 1), y1c = min(max(y0 + 1, 0), HH - 1);
    off0 = y0c * 64 + xa;
    off1 = y1c * 64 + xa;
    h0 = pkh2(wA0, wB0);
    h1 = pkh2(wA1, wB1);
}

// 4-channel accumulate: rows q0 (weight h0) and q1 (weight h1).
__device__ __forceinline__ void dot8(uint4 q0, uint4 q1, uint32_t h0,
                                     uint32_t h1, float& a0, float& a1,
                                     float& a2, float& a3) {
    a0 = fdot2f(q0.x, h0, a0);
    a1 = fdot2f(q0.y, h0, a1);
    a2 = fdot2f(q0.z, h0, a2);
    a3 = fdot2f(q0.w, h0, a3);
    a0 = fdot2f(q1.x, h1, a0);
    a1 = fdot2f(q1.y, h1, a1);
    a2 = fdot2f(q1.z, h1, a2);
    a3 = fdot2f(q1.w, h1, a3);
}

// ---------------------------------------------------------------------------
// Main kernel v15: block = (key, tl, yq3); key = ((b*2+cg2)<<1)|yhalf drives
// XCD placement (blk&7 -> XCD). Thread handles 4 channels for t_lo = tl and
// t_hi = 31-tl. Two-loop branch-free structure, 8 gathers per body.
// 1024 blocks x 256 threads; __launch_bounds__(256,4) -> VGPR <= 128.
// ---------------------------------------------------------------------------
__global__ __launch_bounds__(256, 4) void warp_pscan_v15(
    const float* __restrict__ cum, const uint32_t* __restrict__ planes,
    float* __restrict__ out) {
    int blk = blockIdx.x;   // 1024 = rest(128) * 8 + key(8)
    int tid = threadIdx.x;
    int key  = blk & 7;
    int rest = blk >> 3;    // [0,128)
    int yhalf = key & 1;
    int bc = key >> 1;      // b*2 + cg2
    int cg2 = bc & 1;
    int b   = bc >> 1;
    int tl  = rest >> 3;    // [0,16)
    int yq  = yhalf * 8 + (rest & 7);  // [0,16): 4-row group
    int x   = tid & 63;
    int t_lo = tl, t_hi = (LL - 1) - tl;
    int pix = yq * 256 + tid;  // y = yq*4 + (tid>>6)

    float gx = -1.0f + (float)(2 * x + 1) * (1.0f / WW);
    int y = pix >> 6;
    float gy = -1.0f + (float)(2 * y + 1) * (1.0f / HH);

    const float* cumb = cum + (size_t)b * LL * 2 * HWL + pix;
    float ctxlo = cumb[(size_t)(2 * t_lo) * HWL];
    float ctylo = cumb[(size_t)(2 * t_lo + 1) * HWL];
    float ctxhi = cumb[(size_t)(2 * t_hi) * HWL];
    float ctyhi = cumb[(size_t)(2 * t_hi + 1) * HWL];

    float gx1 = gx + 1.0f, gy1 = gy + 1.0f;
    float axl = gx1 + ctxlo, ayl = gy1 + ctylo;
    float axh = gx1 + ctxhi, ayh = gy1 + ctyhi;

    float l0 = 0.0f, l1 = 0.0f, l2 = 0.0f, l3 = 0.0f;
    float g0 = 0.0f, g1 = 0.0f, g2 = 0.0f, g3 = 0.0f;

    const uint4* plb =
        reinterpret_cast<const uint4*>(planes) + ((size_t)(b * LL) * 2 + cg2) * 4096;
    const size_t KS = 2 * 4096;  // uint4 recs per k-step

    int k = 0;
    // ---- Loop A: k-pairs, both t_lo and t_hi (8 gathers/body) -------------
    for (; k + 1 <= t_lo; k += 2) {
        float cx0 = cumb[(size_t)(2 * k) * HWL];
        float cy0 = cumb[(size_t)(2 * k + 1) * HWL];
        float cx1 = cumb[(size_t)(2 * k + 2) * HWL];
        float cy1 = cumb[(size_t)(2 * k + 3) * HWL];
        const uint4* r0 = plb + (size_t)k * KS;
        const uint4* r1 = r0 + KS;
        int ha0, ha1, la0, la1, hb0, hb1, lb0, lb1;
        uint32_t hw0a, hw1a, lw0a, lw1a, hw0b, hw1b, lw0b, lw1b;
        prep_s3(axh, ayh, cx0, cy0, ha0, ha1, hw0a, hw1a);
        prep_s3(axl, ayl, cx0, cy0, la0, la1, lw0a, lw1a);
        prep_s3(axh, ayh, cx1, cy1, hb0, hb1, hw0b, hw1b);
        prep_s3(axl, ayl, cx1, cy1, lb0, lb1, lw0b, lw1b);
        uint4 qh0a = r0[ha0], qh1a = r0[ha1];
        uint4 ql0a = r0[la0], ql1a = r0[la1];
        uint4 qh0b = r1[hb0], qh1b = r1[hb1];
        uint4 ql0b = r1[lb0], ql1b = r1[lb1];
        dot8(qh0a, qh1a, hw0a, hw1a, g0, g1, g2, g3);
        dot8(ql0a, ql1a, lw0a, lw1a, l0, l1, l2, l3);
        dot8(qh0b, qh1b, hw0b, hw1b, g0, g1, g2, g3);
        dot8(ql0b, ql1b, lw0b, lw1b, l0, l1, l2, l3);
    }
    if (k <= t_lo) {  // loop-A tail (single k, both samples)
        float cx0 = cumb[(size_t)(2 * k) * HWL];
        float cy0 = cumb[(size_t)(2 * k + 1) * HWL];
        const uint4* r0 = plb + (size_t)k * KS;
        int ha0, ha1, la0, la1;
        uint32_t hw0, hw1, lw0, lw1;
        prep_s3(axh, ayh, cx0, cy0, ha0, ha1, hw0, hw1);
        prep_s3(axl, ayl, cx0, cy0, la0, la1, lw0, lw1);
        uint4 qh0 = r0[ha0], qh1 = r0[ha1];
        uint4 ql0 = r0[la0], ql1 = r0[la1];
        dot8(qh0, qh1, hw0, hw1, g0, g1, g2, g3);
        dot8(ql0, ql1, lw0, lw1, l0, l1, l2, l3);
        ++k;
    }
    // ---- Loop B: k-quads, hi only (8 gathers/body) --------------------------
    for (; k + 3 <= t_hi; k += 4) {
        float cx0 = cumb[(size_t)(2 * k) * HWL];
        float cy0 = cumb[(size_t)(2 * k + 1) * HWL];
        float cx1 = cumb[(size_t)(2 * k + 2) * HWL];
        float cy1 = cumb[(size_t)(2 * k + 3) * HWL];
        float cx2 = cumb[(size_t)(2 * k + 4) * HWL];
        float cy2 = cumb[(size_t)(2 * k + 5) * HWL];
        float cx3 = cumb[(size_t)(2 * k + 6) * HWL];
        float cy3 = cumb[(size_t)(2 * k + 7) * HWL];
        const uint4* r0 = plb + (size_t)k * KS;
        const uint4* r1 = r0 + KS;
        const uint4* r2 = r1 + KS;
        const uint4* r3 = r2 + KS;
        int o00, o01, o10, o11, o20, o21, o30, o31;
        uint32_t w00, w01, w10, w11, w20, w21, w30, w31;
        prep_s3(axh, ayh, cx0, cy0, o00, o01, w00, w01);
        prep_s3(axh, ayh, cx1, cy1, o10, o11, w10, w11);
        prep_s3(axh, ayh, cx2, cy2, o20, o21, w20, w21);
        prep_s3(axh, ayh, cx3, cy3, o30, o31, w30, w31);
        uint4 q00 = r0[o00], q01 = r0[o01];
        uint4 q10 = r1[o10], q11 = r1[o11];
        uint4 q20 = r2[o20], q21 = r2[o21];
        uint4 q30 = r3[o30], q31 = r3[o31];
        dot8(q00, q01, w00, w01, g0, g1, g2, g3);
        dot8(q10, q11, w10, w11, g0, g1, g2, g3);
        dot8(q20, q21, w20, w21, g0, g1, g2, g3);
        dot8(q30, q31, w30, w31, g0, g1, g2, g3);
    }
    for (; k <= t_hi; ++k) {  // loop-B tail (1-3 singles)
        float cx = cumb[(size_t)(2 * k) * HWL];
        float cy = cumb[(size_t)(2 * k + 1) * HWL];
        const uint4* r0 = plb + (size_t)k * KS;
        int o0, o1;
        uint32_t w0, w1;
        prep_s3(axh, ayh, cx, cy, o0, o1, w0, w1);
        uint4 q0 = r0[o0], q1 = r0[o1];
        dot8(q0, q1, w0, w1, g0, g1, g2, g3);
    }

    int c0 = cg2 * 4;
    float* ol = out + ((size_t)(b * LL + t_lo) * CC + c0) * HWL + pix;
    ol[0]               = l0;
    ol[(size_t)1 * HWL] = l1;
    ol[(size_t)2 * HWL] = l2;
    ol[(size_t)3 * HWL] = l3;
    float* oh = out + ((size_t)(b * LL + t_hi) * CC + c0) * HWL + pix;
    oh[0]               = g0;
    oh[(size_t)1 * HWL] = g1;
    oh[(size_t)2 * HWL] = g2;
    oh[(size_t)3 * HWL] = g3;
}

// ---------------------------------------------------------------------------
// Fallback (ws too small): fp32 scalar path, original layouts (r5-proven).
// ---------------------------------------------------------------------------
__global__ __launch_bounds__(256) void warp_pscan_fb(
    const float* __restrict__ cum, const float* __restrict__ images,
    float* __restrict__ out) {
    int idx = blockIdx.x * blockDim.x + threadIdx.x;
    if (idx >= BB * LL * HWL) return;
    int x  = idx & (WW - 1);
    int y  = (idx >> 6) & (HH - 1);
    int tl = (idx >> 12) & (LL - 1);
    int b  = idx >> 17;
    int t = (tl < 16) ? tl : (47 - tl);
    int pix = y * WW + x;
    float gx = -1.0f + (float)(2 * x + 1) * (1.0f / WW);
    float gy = -1.0f + (float)(2 * y + 1) * (1.0f / HH);
    const float* cumb = cum + (size_t)b * LL * 2 * HWL + pix;
    float ctx = cumb[(size_t)(2 * t) * HWL];
    float cty = cumb[(size_t)(2 * t + 1) * HWL];
    float acc[CC];
#pragma unroll
    for (int c = 0; c < CC; ++c) acc[c] = 0.0f;
    const float* imgb = images + (size_t)b * LL * CC * HWL;
    for (int k = 0; k <= t; ++k) {
        float dx = ctx - cumb[(size_t)(2 * k) * HWL];
        float dy = cty - cumb[(size_t)(2 * k + 1) * HWL];
        float g0 = gx + dx, g1 = gy + dy;
        float a = g0 + 1.0f, h = a * 0.5f;
        float rem = (h - floorf(h)) * 2.0f;
        float ix = fmaf(rem, 32.0f, -0.5f);
        float iy = fmaf(g1 + 1.0f, 32.0f, -0.5f);
        float x0f = floorf(ix), y0f = floorf(iy);
        float wx1 = ix - x0f, wy1 = iy - y0f;
        float wx0 = 1.0f - wx1, wy0 = 1.0f - wy1;
        int x0 = (int)x0f, y0 = (int)y0f;
        bool vx0 = x0 >= 0, vx1 = x0 < WW - 1;
        bool vy0 = (y0 >= 0) & (y0 < HH), vy1 = (y0 >= -1) & (y0 < HH - 1);
        int x0c = max(x0, 0), x1c = min(x0 + 1, WW - 1);
        int y0c = min(max(y0, 0), HH - 1), y1c = min(max(y0 + 1, 0), HH - 1);
        float w00 = (vx0 && vy0) ? wx0 * wy0 : 0.0f;
        float w10 = (vx1 && vy0) ? wx1 * wy0 : 0.0f;
        float w01 = (vx0 && vy1) ? wx0 * wy1 : 0.0f;
        float w11 = (vx1 && vy1) ? wx1 * wy1 : 0.0f;
        int o00 = y0c * WW + x0c, o10 = y0c * WW + x1c;
        int o01 = y1c * WW + x0c, o11 = y1c * WW + x1c;
        const float* ip = imgb + (size_t)k * CC * HWL;
#pragma unroll
        for (int c = 0; c < CC; ++c) {
            const float* ic = ip + (size_t)c * HWL;
            acc[c] += w00 * ic[o00] + w10 * ic[o10] + w01 * ic[o01] +
                      w11 * ic[o11];
        }
    }
    float* op = out + ((size_t)(b * LL + t) * CC) * HWL + pix;
#pragma unroll
    for (int c = 0; c < CC; ++c) op[(size_t)c * HWL] = acc[c];
}

extern "C" void kernel_launch(void* const* d_in, const int* in_sizes, int n_in,
                              void* d_out, int out_size, void* d_ws,
                              size_t ws_size, hipStream_t stream) {
    const float* flows  = (const float*)d_in[0];
    const float* images = (const float*)d_in[1];
    float* out = (float*)d_out;

    const size_t cum_bytes   = (size_t)BB * LL * 2 * HWL * sizeof(float);  // 2 MiB
    const size_t plane_bytes = (size_t)BB * LL * 2 * 4096 * 16;            // 8 MiB
    float* cum       = (float*)d_ws;
    uint32_t* planes = (uint32_t*)((char*)d_ws + cum_bytes);
    bool full = (ws_size >= cum_bytes + plane_bytes);

    if (full) {
        int nprep = CUM_BLOCKS + 1024;  // 64 cum blocks + 1024 repack blocks
        prep_kernel<<<nprep, 256, 0, stream>>>(flows, images, cum, planes);
        warp_pscan_v15<<<1024, 256, 0, stream>>>(cum, planes, out);
    } else {
        prep_kernel<<<CUM_BLOCKS, 256, 0, stream>>>(flows, images, cum,
                                                    planes);
        int n3 = BB * LL * HWL;
        warp_pscan_fb<<<(n3 + 255) / 256, 256, 0, stream>>>(cum, images, out);
    }
}